// Round 2
// baseline (5703.598 us; speedup 1.0000x reference)
//
#include <hip/hip_runtime.h>
#include <hip/hip_bf16.h>
#include <stdint.h>
#include <stddef.h>

// ---------------------------------------------------------------------------
// Seq2Seq BiGRU: B=256 T=512 F=64 H=256 (2-layer bidir encoder),
// decoder DH=512 2-layer, OSL=20, OUT=2.
//
// Round-4 structure (= round-3 + hardened group barrier):
//  - prep_all: all weight casts + weff/beff/ov prep + barrier-counter zeroing
//    in ONE launch (was 8).
//  - gemm_gi / gru_scan unchanged (scan is MFMA-roofline-bound on its 32 CUs).
//  - dec_fused: the entire 20-step x 2-cell decoder in ONE persistent launch
//    (was 40). 128 WGs = 16 batch-groups x 8 j-blocks; after each cell the
//    8 WGs of a group sync via a device-scope atomic barrier.
//    HARDENED: spin reads use atomicAdd(cnt,0) (RMW at coherence point,
//    immune to stale-XCD-L2 loads), last arriver skips the spin, and the
//    spin is bounded (2^18 iters) so a broken barrier FAILS instead of
//    hanging the container.
// ---------------------------------------------------------------------------

typedef __bf16 bf16_t;
typedef bf16_t bf16x8 __attribute__((ext_vector_type(8)));
typedef float  f32x4  __attribute__((ext_vector_type(4)));

#define B_   256
#define T_   512
#define F_   64
#define H_   256
#define G_   768      // 3*H
#define DH_  512
#define DG_  1536     // 3*DH
#define OSL_ 20

__device__ __forceinline__ float sigm(float x) {
    float e = __builtin_amdgcn_exp2f(-1.442695040888963f * x);
    return __builtin_amdgcn_rcpf(1.0f + e);
}
__device__ __forceinline__ float tanh_(float x) {
    float e = __builtin_amdgcn_exp2f(-2.885390081777927f * x);
    return __builtin_amdgcn_rcpf(1.0f + e) * 2.0f - 1.0f;
}

__device__ __forceinline__ bf16x8 load_f32x8_as_bf16(const float* p) {
    f32x4 u = *(const f32x4*)p;
    f32x4 v = *(const f32x4*)(p + 4);
    bf16x8 r;
    r[0]=(bf16_t)u[0]; r[1]=(bf16_t)u[1]; r[2]=(bf16_t)u[2]; r[3]=(bf16_t)u[3];
    r[4]=(bf16_t)v[0]; r[5]=(bf16_t)v[1]; r[6]=(bf16_t)v[2]; r[7]=(bf16_t)v[3];
    return r;
}

// ------------------------------- fused prep --------------------------------
// blockIdx.y picks segment: 0-6 weight casts, 7 = weff/beff/ov + bar zeroing.
__global__ __launch_bounds__(256) void prep_all(
    const float* __restrict__ s0, const float* __restrict__ s1,
    const float* __restrict__ s2, const float* __restrict__ s3,
    const float* __restrict__ s4, const float* __restrict__ s5,
    const float* __restrict__ s6,
    bf16_t* __restrict__ d0, bf16_t* __restrict__ d1, bf16_t* __restrict__ d2,
    bf16_t* __restrict__ d3, bf16_t* __restrict__ d4, bf16_t* __restrict__ d5,
    bf16_t* __restrict__ d6,
    const float* __restrict__ wih0d, const float* __restrict__ fcw,
    const float* __restrict__ fcb, const float* __restrict__ bih0d,
    const float* __restrict__ st, bf16_t* __restrict__ weff,
    float* __restrict__ beff, float* __restrict__ ov,
    unsigned int* __restrict__ bar) {
    int i = blockIdx.x * 256 + threadIdx.x;
    switch (blockIdx.y) {
      case 0: if (i < 2*G_*F_)  d0[i] = (bf16_t)s0[i]; break;
      case 1: if (i < 2*G_*H_)  d1[i] = (bf16_t)s1[i]; break;
      case 2: if (i < 2*G_*DH_) d2[i] = (bf16_t)s2[i]; break;
      case 3: if (i < 2*G_*H_)  d3[i] = (bf16_t)s3[i]; break;
      case 4: if (i < DG_*DH_)  d4[i] = (bf16_t)s4[i]; break;
      case 5: if (i < DG_*DH_)  d5[i] = (bf16_t)s5[i]; break;
      case 6: if (i < DG_*DH_)  d6[i] = (bf16_t)s6[i]; break;
      default: {
        if (i < 40 * 16) bar[i] = 0u;
        if (i < DG_*DH_) {
          int g = i >> 9, k = i & 511;
          float a0 = wih0d[g * 2], a1 = wih0d[g * 2 + 1];
          weff[i] = (bf16_t)(a0 * fcw[k] + a1 * fcw[DH_ + k]);
          if (k == 0) {
            beff[g] = a0 * fcb[0] + a1 * fcb[1] + bih0d[g];
            ov[g]   = a0 * st[0]  + a1 * st[1]  + bih0d[g];
          }
        }
      } break;
    }
}

// --------------------------- gi chunk GEMM ---------------------------------
__global__ __launch_bounds__(256) void gemm_gi(
    const float* __restrict__ x, const bf16_t* __restrict__ xcat,
    const bf16_t* __restrict__ Bt, bf16_t* __restrict__ gi, int t0, int K) {
    __shared__ bf16_t As[128 * 64];
    __shared__ bf16_t Bs[128 * 64];
    int m0 = blockIdx.x * 128, n0 = blockIdx.y * 128;
    int tid = threadIdx.x;
    int lane = tid & 63, w = tid >> 6;
    int col = lane & 15, quad = lane >> 4;
    int qm = (w >> 1) * 64, qn = (w & 1) * 64;

    int tl = m0 >> 8;              // local chunk time (constant per block)
    int bbase = m0 & 255;          // batch base (0 or 128)
    int t_real = t0 + tl;
    if (n0 >= 768) t_real = (T_ - 1) - t_real;

    f32x4 acc[4][4] = {};
    for (int k0 = 0; k0 < K; k0 += 64) {
        __syncthreads();
#pragma unroll
        for (int i = 0; i < 4; i++) {
            int c = i * 256 + tid;
            int m = c >> 3, kc = c & 7;
            int kcs = kc ^ (m & 7);   // XOR swizzle at source
            bf16x8 av;
            if (K == 64) {
                av = load_f32x8_as_bf16(x + ((size_t)(bbase + m) * T_ + t_real) * F_ + kcs * 8);
            } else {
                av = *(const bf16x8*)(xcat + ((size_t)t_real * B_ + bbase + m) * DH_ + k0 + kcs * 8);
            }
            *(bf16x8*)(&As[c * 8]) = av;
            *(bf16x8*)(&Bs[c * 8]) = *(const bf16x8*)(Bt + (size_t)(n0 + m) * K + k0 + kcs * 8);
        }
        __syncthreads();
#pragma unroll
        for (int kt = 0; kt < 2; kt++) {
            bf16x8 a[4], b[4];
#pragma unroll
            for (int mt = 0; mt < 4; mt++) {
                int r = qm + mt * 16 + col;
                a[mt] = *(const bf16x8*)(&As[(r * 8 + ((kt * 4 + quad) ^ (r & 7))) * 8]);
                int rn = qn + mt * 16 + col;
                b[mt] = *(const bf16x8*)(&Bs[(rn * 8 + ((kt * 4 + quad) ^ (rn & 7))) * 8]);
            }
#pragma unroll
            for (int mt = 0; mt < 4; mt++)
#pragma unroll
                for (int nt = 0; nt < 4; nt++)
                    acc[mt][nt] = __builtin_amdgcn_mfma_f32_16x16x32_bf16(a[mt], b[nt], acc[mt][nt], 0, 0, 0);
        }
    }
#pragma unroll
    for (int mt = 0; mt < 4; mt++)
#pragma unroll
        for (int nt = 0; nt < 4; nt++)
#pragma unroll
            for (int i = 0; i < 4; i++) {
                int row = m0 + qm + mt * 16 + quad * 4 + i;
                int cg  = n0 + qn + nt * 16 + col;
                gi[(size_t)row * DG_ + cg] = (bf16_t)acc[mt][nt][i];
            }
}

// ------------------------------ GRU scan (chunked) -------------------------
__global__ __launch_bounds__(512) void gru_scan(
    const bf16_t* __restrict__ gi, int t0, int tc,
    const bf16_t* __restrict__ whh,
    const float* __restrict__ bih, const float* __restrict__ bhh,
    float* __restrict__ hstate, bf16_t* __restrict__ y, float* __restrict__ hT) {
    __shared__ bf16_t gi_lds[16 * 768];       // [b][768]
    __shared__ bf16_t h_lds[2 * 16 * 264];    // [par][b][256+8 pad]

    int dir = blockIdx.x >> 4;
    int b0  = (blockIdx.x & 15) * 16;
    int tid = threadIdx.x;
    int w = tid >> 6, lane = tid & 63, col = lane & 15, quad = lane >> 4;

    // resident recurrent weights
    bf16x8 wf[3][2][8];
    const bf16_t* wbase = whh + (size_t)dir * G_ * H_;
#pragma unroll
    for (int g = 0; g < 3; g++)
#pragma unroll
        for (int nt = 0; nt < 2; nt++) {
            int row = g * 256 + w * 32 + nt * 16 + col;
#pragma unroll
            for (int kt = 0; kt < 8; kt++)
                wf[g][nt][kt] = *(const bf16x8*)(wbase + (size_t)row * H_ + kt * 32 + quad * 8);
        }
    // biases
    float brz[2][2], bin_[2], bhn[2];
#pragma unroll
    for (int nt = 0; nt < 2; nt++) {
        int j = w * 32 + nt * 16 + col;
        brz[0][nt] = bih[dir * G_ + j] + bhh[dir * G_ + j];
        brz[1][nt] = bih[dir * G_ + 256 + j] + bhh[dir * G_ + 256 + j];
        bin_[nt]   = bih[dir * G_ + 512 + j];
        bhn[nt]    = bhh[dir * G_ + 512 + j];
    }
    // gi staging map: 1536 chunks of 8 bf16 cover [16][768]
    int bb[3], oo[3];
#pragma unroll
    for (int it = 0; it < 3; it++) {
        int c = it * 512 + tid;
        bb[it] = c / 96;
        oo[it] = (c % 96) * 8;
    }
    // init h (zero at t0==0 else from hstate), fp32 carry in registers
    float hold[2][4];
#pragma unroll
    for (int nt = 0; nt < 2; nt++)
#pragma unroll
        for (int i = 0; i < 4; i++) {
            int j = w * 32 + nt * 16 + col;
            hold[nt][i] = t0 ? hstate[dir * 65536 + (b0 + quad * 4 + i) * 256 + j] : 0.0f;
        }
    for (int i = tid; i < 16 * 264; i += 512) {
        int b = i / 264, j = i % 264;
        float v = (t0 && j < 256) ? hstate[dir * 65536 + (b0 + b) * 256 + j] : 0.0f;
        h_lds[i] = (bf16_t)v;
    }
    // stage gi row 0
#pragma unroll
    for (int it = 0; it < 3; it++) {
        int c = it * 512 + tid;
        *(bf16x8*)(&gi_lds[c * 8]) =
            *(const bf16x8*)(gi + ((size_t)0 * B_ + b0 + bb[it]) * DG_ + dir * G_ + oo[it]);
    }
    __syncthreads();

    for (int s = 0; s < tc; s++) {
        int par = s & 1;
        int t = t0 + s;
        int sn = (s + 1 < tc) ? (s + 1) : s;

        // prefetch next gi row into registers
        bf16x8 pg[3];
#pragma unroll
        for (int it = 0; it < 3; it++)
            pg[it] = *(const bf16x8*)(gi + ((size_t)sn * B_ + b0 + bb[it]) * DG_ + dir * G_ + oo[it]);

        // gh = h @ Whh^T
        f32x4 acc[3][2] = {};
        const bf16_t* hcur = &h_lds[par * 4224];
#pragma unroll
        for (int kt = 0; kt < 8; kt++) {
            bf16x8 af = *(const bf16x8*)(hcur + col * 264 + kt * 32 + quad * 8);
#pragma unroll
            for (int g = 0; g < 3; g++)
#pragma unroll
                for (int nt = 0; nt < 2; nt++)
                    acc[g][nt] = __builtin_amdgcn_mfma_f32_16x16x32_bf16(af, wf[g][nt][kt], acc[g][nt], 0, 0, 0);
        }

        // gates + state update (fp32 carry in hold[][])
        bf16_t* hnext = &h_lds[(par ^ 1) * 4224];
        int tp = dir ? (T_ - 1 - t) : t;
#pragma unroll
        for (int nt = 0; nt < 2; nt++) {
            int j = w * 32 + nt * 16 + col;
#pragma unroll
            for (int i = 0; i < 4; i++) {
                int b = quad * 4 + i;
                float gr = acc[0][nt][i] + (float)gi_lds[b * 768 + j]       + brz[0][nt];
                float gz = acc[1][nt][i] + (float)gi_lds[b * 768 + 256 + j] + brz[1][nt];
                float gn = (float)gi_lds[b * 768 + 512 + j] + bin_[nt];
                float r = sigm(gr), z = sigm(gz);
                float n = tanh_(gn + r * (acc[2][nt][i] + bhn[nt]));
                float hv = (1.0f - z) * n + z * hold[nt][i];
                hold[nt][i] = hv;
                hnext[b * 264 + j] = (bf16_t)hv;
                if (y) y[((size_t)tp * B_ + b0 + b) * DH_ + dir * H_ + j] = (bf16_t)hv;
                if (t == T_ - 1) hT[(size_t)(b0 + b) * DH_ + dir * H_ + j] = hv;
            }
        }
        __syncthreads();   // everyone done reading gi_lds(s) and h_lds
        // commit prefetched gi row (single buffer)
#pragma unroll
        for (int it = 0; it < 3; it++)
            *(bf16x8*)(&gi_lds[(it * 512 + tid) * 8]) = pg[it];
        __syncthreads();   // gi_lds(s+1) visible
    }
    // persist h for next chunk
#pragma unroll
    for (int nt = 0; nt < 2; nt++)
#pragma unroll
        for (int i = 0; i < 4; i++) {
            int j = w * 32 + nt * 16 + col;
            hstate[dir * 65536 + (b0 + quad * 4 + i) * 256 + j] = hold[nt][i];
        }
}

// ----------------------------- fused decoder -------------------------------
// 128 WGs = 16 batch-groups (grp = blockIdx.x % 16, 16 rows each) x 8 j-blocks
// (jblk = blockIdx.x / 16, 64 units each). All 20 steps x 2 cells in one
// launch; after each cell the 8 WGs of a group sync via device-scope atomic
// barrier (fresh counter per phase, zeroed by prep_all each iteration).
// Spin reads are atomic RMWs (atomicAdd(cnt,0)): RMWs always execute at the
// coherence point and can never be served from a stale per-XCD L2 line.
// Spin is bounded so a broken barrier produces a wrong answer, not a hang.

__device__ __forceinline__ void group_barrier(unsigned int* cnt) {
    __threadfence();                 // release this thread's h stores (agent)
    __syncthreads();                 // all threads of WG fenced before arrival
    if (threadIdx.x == 0) {
        unsigned int old = atomicAdd(cnt, 1u);   // device-scope RMW
        if (old < 7u) {                          // not the last arriver
            unsigned int spins = 0;
            while (atomicAdd(cnt, 0u) < 8u && ++spins < (1u << 18))
                __builtin_amdgcn_s_sleep(1);
        }
    }
    __syncthreads();
    __threadfence();                 // acquire: invalidate for partner h reads
}

__device__ __forceinline__ void dec_cell_body(
    int b0, int j, int quad, int col,
    const float* __restrict__ xsrc, const bf16_t* __restrict__ Wx,
    const float* __restrict__ bx, const float* __restrict__ ovv,
    const float* __restrict__ hin, const bf16_t* __restrict__ Wh,
    const float* __restrict__ bh, float* __restrict__ hout,
    float* __restrict__ hist) {
    bool do_gi = (ovv == nullptr);
    f32x4 agi[3] = {}, agh[3] = {};
#pragma unroll 4
    for (int kt = 0; kt < 16; kt++) {
        bf16x8 ah = load_f32x8_as_bf16(hin + (size_t)(b0 + col) * DH_ + kt * 32 + quad * 8);
#pragma unroll
        for (int g = 0; g < 3; g++) {
            bf16x8 bw = *(const bf16x8*)(Wh + (size_t)(g * DH_ + j) * DH_ + kt * 32 + quad * 8);
            agh[g] = __builtin_amdgcn_mfma_f32_16x16x32_bf16(ah, bw, agh[g], 0, 0, 0);
        }
        if (do_gi) {
            bf16x8 ax = load_f32x8_as_bf16(xsrc + (size_t)(b0 + col) * DH_ + kt * 32 + quad * 8);
#pragma unroll
            for (int g = 0; g < 3; g++) {
                bf16x8 bw = *(const bf16x8*)(Wx + (size_t)(g * DH_ + j) * DH_ + kt * 32 + quad * 8);
                agi[g] = __builtin_amdgcn_mfma_f32_16x16x32_bf16(ax, bw, agi[g], 0, 0, 0);
            }
        }
    }
#pragma unroll
    for (int i = 0; i < 4; i++) {
        int b = b0 + quad * 4 + i;
        float gr, gz, gn;
        if (do_gi) {
            gr = agi[0][i] + bx[j];
            gz = agi[1][i] + bx[DH_ + j];
            gn = agi[2][i] + bx[2 * DH_ + j];
        } else {
            gr = ovv[j]; gz = ovv[DH_ + j]; gn = ovv[2 * DH_ + j];
        }
        float hr = agh[0][i] + bh[j];
        float hz = agh[1][i] + bh[DH_ + j];
        float hn = agh[2][i] + bh[2 * DH_ + j];
        float r = sigm(gr + hr), z = sigm(gz + hz);
        float n = tanh_(gn + r * hn);
        float hold = hin[(size_t)b * DH_ + j];
        float hv = (1.0f - z) * n + z * hold;
        hout[(size_t)b * DH_ + j] = hv;
        if (hist) hist[(size_t)b * DH_ + j] = hv;
    }
}

__global__ __launch_bounds__(256) void dec_fused(
    const bf16_t* __restrict__ weff, const float* __restrict__ beff,
    const float* __restrict__ ov,
    const bf16_t* __restrict__ wdhh0, const float* __restrict__ dbhh0,
    const bf16_t* __restrict__ wdih1, const float* __restrict__ dbih1,
    const bf16_t* __restrict__ wdhh1, const float* __restrict__ dbhh1,
    float* h0a, float* h0b, float* h1a, float* h1b,
    float* __restrict__ hist, unsigned int* __restrict__ bar) {
    int grp  = blockIdx.x & 15;       // partner WGs 16 apart -> same XCD (%8)
    int b0 = grp * 16;
    int tid = threadIdx.x, w = tid >> 6, lane = tid & 63;
    int col = lane & 15, quad = lane >> 4;
    int j = (blockIdx.x >> 4) * 64 + w * 16 + col;

    float *h0c = h0a, *h0n = h0b, *h1c = h1a, *h1n = h1b;
    int ph = 0;
    for (int t = 0; t < OSL_; t++) {
        // cell0: gi = (t==0 ? ov : Weff @ h1) ; gh = h0 @ Whh0^T
        dec_cell_body(b0, j, quad, col,
                      h1c, weff, beff, (t == 0 ? ov : nullptr),
                      h0c, wdhh0, dbhh0, h0n, nullptr);
        { float* tmp = h0c; h0c = h0n; h0n = tmp; }
        group_barrier(bar + (ph++) * 16 + grp);

        // cell1: gi = h0' @ Wih1^T ; gh = h1 @ Whh1^T ; writes hist[t]
        dec_cell_body(b0, j, quad, col,
                      h0c, wdih1, dbih1, nullptr,
                      h1c, wdhh1, dbhh1, h1n,
                      hist + (size_t)t * B_ * DH_);
        { float* tmp = h1c; h1c = h1n; h1n = tmp; }
        if (t < OSL_ - 1) group_barrier(bar + (ph++) * 16 + grp);
    }
}

// ------------------------------- FC head -----------------------------------
__global__ __launch_bounds__(256) void fc_all(
    const float* __restrict__ hist, const float* __restrict__ fcw,
    const float* __restrict__ fcb, float* __restrict__ out) {
    int t  = blockIdx.x >> 4;
    int b0 = (blockIdx.x & 15) * 16;
    int tid = threadIdx.x;
    int bl = tid >> 4, o = (tid >> 3) & 1, part = tid & 7;
    const float* hp = hist + ((size_t)t * B_ + b0 + bl) * DH_;
    const float* wp = fcw + o * DH_;
    float s = 0.0f;
    for (int k = part * 64; k < part * 64 + 64; k += 4) {
        f32x4 hv = *(const f32x4*)(hp + k);
        f32x4 wv = *(const f32x4*)(wp + k);
        s += hv[0] * wv[0] + hv[1] * wv[1] + hv[2] * wv[2] + hv[3] * wv[3];
    }
    s += __shfl_down(s, 4); s += __shfl_down(s, 2); s += __shfl_down(s, 1);
    if (part == 0) out[(size_t)(b0 + bl) * (OSL_ * 2) + t * 2 + o] = s + fcb[o];
}

// ------------------------------ launcher -----------------------------------

// fixed workspace offsets (bytes); gi chunk goes last (ws_size-adaptive)
#define OFF_WIH0E 0ull
#define OFF_WHH0E 196608ull
#define OFF_WIH1E 983040ull
#define OFF_WHH1E 2555904ull
#define OFF_WDHH0 3342336ull
#define OFF_WDIH1 4915200ull
#define OFF_WDHH1 6488064ull
#define OFF_WEFF  8060928ull
#define OFF_BEFF  9633792ull
#define OFF_BAR   9641984ull    // 40 phases x 16 groups x u32 = 2560 B
#define OFF_OV    9658368ull
#define OFF_H0A   9682944ull
#define OFF_H0B   10207232ull
#define OFF_H1A   10731520ull
#define OFF_H1B   11255808ull
#define OFF_HST   11780096ull
#define OFF_HIST  12304384ull
#define OFF_XCAT  22790144ull
#define OFF_GI    157007872ull

extern "C" void kernel_launch(void* const* d_in, const int* in_sizes, int n_in,
                              void* d_out, int out_size, void* d_ws, size_t ws_size,
                              hipStream_t stream) {
    const float* x      = (const float*)d_in[0];
    const float* st     = (const float*)d_in[1];
    const float* eWih0  = (const float*)d_in[2];
    const float* eWhh0  = (const float*)d_in[3];
    const float* ebih0  = (const float*)d_in[4];
    const float* ebhh0  = (const float*)d_in[5];
    const float* eWih1  = (const float*)d_in[6];
    const float* eWhh1  = (const float*)d_in[7];
    const float* ebih1  = (const float*)d_in[8];
    const float* ebhh1  = (const float*)d_in[9];
    const float* dWih0  = (const float*)d_in[10];
    const float* dWhh0  = (const float*)d_in[11];
    const float* dbih0  = (const float*)d_in[12];
    const float* dbhh0  = (const float*)d_in[13];
    const float* dWih1  = (const float*)d_in[14];
    const float* dWhh1  = (const float*)d_in[15];
    const float* dbih1  = (const float*)d_in[16];
    const float* dbhh1  = (const float*)d_in[17];
    const float* fcW    = (const float*)d_in[18];
    const float* fcb    = (const float*)d_in[19];

    char* ws = (char*)d_ws;
    bf16_t* wih0e = (bf16_t*)(ws + OFF_WIH0E);
    bf16_t* whh0e = (bf16_t*)(ws + OFF_WHH0E);
    bf16_t* wih1e = (bf16_t*)(ws + OFF_WIH1E);
    bf16_t* whh1e = (bf16_t*)(ws + OFF_WHH1E);
    bf16_t* wdhh0 = (bf16_t*)(ws + OFF_WDHH0);
    bf16_t* wdih1 = (bf16_t*)(ws + OFF_WDIH1);
    bf16_t* wdhh1 = (bf16_t*)(ws + OFF_WDHH1);
    bf16_t* weff  = (bf16_t*)(ws + OFF_WEFF);
    float*  beff  = (float*)(ws + OFF_BEFF);
    unsigned int* bar = (unsigned int*)(ws + OFF_BAR);
    float*  ovp   = (float*)(ws + OFF_OV);
    float*  h0buf[2] = { (float*)(ws + OFF_H0A), (float*)(ws + OFF_H0B) };
    float*  h1buf[2] = { (float*)(ws + OFF_H1A), (float*)(ws + OFF_H1B) };
    float*  hstate = (float*)(ws + OFF_HST);
    float*  hist  = (float*)(ws + OFF_HIST);
    bf16_t* xcat  = (bf16_t*)(ws + OFF_XCAT);
    bf16_t* gi    = (bf16_t*)(ws + OFF_GI);

    // pick largest chunk length that fits the workspace
    int Tc = 512;
    while (Tc > 8 && OFF_GI + (unsigned long long)Tc * 786432ull > (unsigned long long)ws_size)
        Tc >>= 1;
    int nch = T_ / Tc;

    // --- prep (one launch: 7 casts + weff/beff/ov + barrier zeroing) ---
    prep_all<<<dim3(3072, 8), 256, 0, stream>>>(
        eWih0, eWhh0, eWih1, eWhh1, dWhh0, dWih1, dWhh1,
        wih0e, whh0e, wih1e, whh1e, wdhh0, wdih1, wdhh1,
        dWih0, fcW, fcb, dbih0, st, weff, beff, ovp, bar);

    // --- encoder layer 0 (gi from x, K=64) ---
    for (int c = 0; c < nch; c++) {
        gemm_gi<<<dim3(Tc * 2, 12), 256, 0, stream>>>(x, nullptr, wih0e, gi, c * Tc, 64);
        gru_scan<<<32, 512, 0, stream>>>(gi, c * Tc, Tc, whh0e, ebih0, ebhh0, hstate, xcat, h0buf[0]);
    }
    // --- encoder layer 1 (gi from xcat, K=512) ---
    for (int c = 0; c < nch; c++) {
        gemm_gi<<<dim3(Tc * 2, 12), 256, 0, stream>>>(nullptr, xcat, wih1e, gi, c * Tc, 512);
        gru_scan<<<32, 512, 0, stream>>>(gi, c * Tc, Tc, whh1e, ebih1, ebhh1, hstate, nullptr, h1buf[0]);
    }

    // --- decoder: all 20 steps x 2 cells in one persistent launch ---
    dec_fused<<<128, 256, 0, stream>>>(weff, beff, ovp,
                                       wdhh0, dbhh0, wdih1, dbih1, wdhh1, dbhh1,
                                       h0buf[0], h0buf[1], h1buf[0], h1buf[1],
                                       hist, bar);

    fc_all<<<OSL_ * 16, 256, 0, stream>>>(hist, fcW, fcb, (float*)d_out);
}

// Round 3
// 4797.795 us; speedup vs baseline: 1.1888x; 1.1888x over previous
//
#include <hip/hip_runtime.h>
#include <hip/hip_bf16.h>
#include <stdint.h>
#include <stddef.h>

// ---------------------------------------------------------------------------
// Seq2Seq BiGRU: B=256 T=512 F=64 H=256 (2-layer bidir encoder),
// decoder DH=512 2-layer, OSL=20, OUT=2.
//
// Round-5 structure:
//  - prep_all / gemm_gi / gru_scan / fc_all unchanged.
//  - dec_persist: full 20x2-cell decoder in one launch, FENCE-FREE barriers.
//    Round-2's dec_fused lost 1688us to agent-fence L2 invalidation (497 MB
//    refetch, 12.7 MB x 40 phases). Now:
//      * h exchanged via per-access coherent atomics (RELAXED/AGENT ->
//        cache-bypass sc bits, no buffer_inv) as packed bf16, double-buffered
//        by step parity; staged once per WG into XOR-swizzled LDS.
//      * f32 h carry in registers (writer of h[b][j] is its own reader).
//      * weights read with plain cached loads -> stay L1/L2-resident across
//        all 40 phases (no cache maintenance anywhere in the loop).
//      * barrier: RELEASE fetch_add sign (waitcnt + L2 writeback only; clean
//        weight lines survive) + RELAXED atomic-load spin, bounded so a
//        broken barrier fails visibly instead of hanging.
// ---------------------------------------------------------------------------

typedef __bf16 bf16_t;
typedef bf16_t bf16x8 __attribute__((ext_vector_type(8)));
typedef float  f32x4  __attribute__((ext_vector_type(4)));

#define B_   256
#define T_   512
#define F_   64
#define H_   256
#define G_   768      // 3*H
#define DH_  512
#define DG_  1536     // 3*DH
#define OSL_ 20

__device__ __forceinline__ float sigm(float x) {
    float e = __builtin_amdgcn_exp2f(-1.442695040888963f * x);
    return __builtin_amdgcn_rcpf(1.0f + e);
}
__device__ __forceinline__ float tanh_(float x) {
    float e = __builtin_amdgcn_exp2f(-2.885390081777927f * x);
    return __builtin_amdgcn_rcpf(1.0f + e) * 2.0f - 1.0f;
}

__device__ __forceinline__ bf16x8 load_f32x8_as_bf16(const float* p) {
    f32x4 u = *(const f32x4*)p;
    f32x4 v = *(const f32x4*)(p + 4);
    bf16x8 r;
    r[0]=(bf16_t)u[0]; r[1]=(bf16_t)u[1]; r[2]=(bf16_t)u[2]; r[3]=(bf16_t)u[3];
    r[4]=(bf16_t)v[0]; r[5]=(bf16_t)v[1]; r[6]=(bf16_t)v[2]; r[7]=(bf16_t)v[3];
    return r;
}

// ------------------------------- fused prep --------------------------------
__global__ __launch_bounds__(256) void prep_all(
    const float* __restrict__ s0, const float* __restrict__ s1,
    const float* __restrict__ s2, const float* __restrict__ s3,
    const float* __restrict__ s4, const float* __restrict__ s5,
    const float* __restrict__ s6,
    bf16_t* __restrict__ d0, bf16_t* __restrict__ d1, bf16_t* __restrict__ d2,
    bf16_t* __restrict__ d3, bf16_t* __restrict__ d4, bf16_t* __restrict__ d5,
    bf16_t* __restrict__ d6,
    const float* __restrict__ wih0d, const float* __restrict__ fcw,
    const float* __restrict__ fcb, const float* __restrict__ bih0d,
    const float* __restrict__ st, bf16_t* __restrict__ weff,
    float* __restrict__ beff, float* __restrict__ ov,
    unsigned int* __restrict__ bar) {
    int i = blockIdx.x * 256 + threadIdx.x;
    switch (blockIdx.y) {
      case 0: if (i < 2*G_*F_)  d0[i] = (bf16_t)s0[i]; break;
      case 1: if (i < 2*G_*H_)  d1[i] = (bf16_t)s1[i]; break;
      case 2: if (i < 2*G_*DH_) d2[i] = (bf16_t)s2[i]; break;
      case 3: if (i < 2*G_*H_)  d3[i] = (bf16_t)s3[i]; break;
      case 4: if (i < DG_*DH_)  d4[i] = (bf16_t)s4[i]; break;
      case 5: if (i < DG_*DH_)  d5[i] = (bf16_t)s5[i]; break;
      case 6: if (i < DG_*DH_)  d6[i] = (bf16_t)s6[i]; break;
      default: {
        if (i < 1024) bar[i] = 0u;
        if (i < DG_*DH_) {
          int g = i >> 9, k = i & 511;
          float a0 = wih0d[g * 2], a1 = wih0d[g * 2 + 1];
          weff[i] = (bf16_t)(a0 * fcw[k] + a1 * fcw[DH_ + k]);
          if (k == 0) {
            beff[g] = a0 * fcb[0] + a1 * fcb[1] + bih0d[g];
            ov[g]   = a0 * st[0]  + a1 * st[1]  + bih0d[g];
          }
        }
      } break;
    }
}

// --------------------------- gi chunk GEMM ---------------------------------
__global__ __launch_bounds__(256) void gemm_gi(
    const float* __restrict__ x, const bf16_t* __restrict__ xcat,
    const bf16_t* __restrict__ Bt, bf16_t* __restrict__ gi, int t0, int K) {
    __shared__ bf16_t As[128 * 64];
    __shared__ bf16_t Bs[128 * 64];
    int m0 = blockIdx.x * 128, n0 = blockIdx.y * 128;
    int tid = threadIdx.x;
    int lane = tid & 63, w = tid >> 6;
    int col = lane & 15, quad = lane >> 4;
    int qm = (w >> 1) * 64, qn = (w & 1) * 64;

    int tl = m0 >> 8;              // local chunk time (constant per block)
    int bbase = m0 & 255;          // batch base (0 or 128)
    int t_real = t0 + tl;
    if (n0 >= 768) t_real = (T_ - 1) - t_real;

    f32x4 acc[4][4] = {};
    for (int k0 = 0; k0 < K; k0 += 64) {
        __syncthreads();
#pragma unroll
        for (int i = 0; i < 4; i++) {
            int c = i * 256 + tid;
            int m = c >> 3, kc = c & 7;
            int kcs = kc ^ (m & 7);   // XOR swizzle at source
            bf16x8 av;
            if (K == 64) {
                av = load_f32x8_as_bf16(x + ((size_t)(bbase + m) * T_ + t_real) * F_ + kcs * 8);
            } else {
                av = *(const bf16x8*)(xcat + ((size_t)t_real * B_ + bbase + m) * DH_ + k0 + kcs * 8);
            }
            *(bf16x8*)(&As[c * 8]) = av;
            *(bf16x8*)(&Bs[c * 8]) = *(const bf16x8*)(Bt + (size_t)(n0 + m) * K + k0 + kcs * 8);
        }
        __syncthreads();
#pragma unroll
        for (int kt = 0; kt < 2; kt++) {
            bf16x8 a[4], b[4];
#pragma unroll
            for (int mt = 0; mt < 4; mt++) {
                int r = qm + mt * 16 + col;
                a[mt] = *(const bf16x8*)(&As[(r * 8 + ((kt * 4 + quad) ^ (r & 7))) * 8]);
                int rn = qn + mt * 16 + col;
                b[mt] = *(const bf16x8*)(&Bs[(rn * 8 + ((kt * 4 + quad) ^ (rn & 7))) * 8]);
            }
#pragma unroll
            for (int mt = 0; mt < 4; mt++)
#pragma unroll
                for (int nt = 0; nt < 4; nt++)
                    acc[mt][nt] = __builtin_amdgcn_mfma_f32_16x16x32_bf16(a[mt], b[nt], acc[mt][nt], 0, 0, 0);
        }
    }
#pragma unroll
    for (int mt = 0; mt < 4; mt++)
#pragma unroll
        for (int nt = 0; nt < 4; nt++)
#pragma unroll
            for (int i = 0; i < 4; i++) {
                int row = m0 + qm + mt * 16 + quad * 4 + i;
                int cg  = n0 + qn + nt * 16 + col;
                gi[(size_t)row * DG_ + cg] = (bf16_t)acc[mt][nt][i];
            }
}

// ------------------------------ GRU scan (chunked) -------------------------
__global__ __launch_bounds__(512) void gru_scan(
    const bf16_t* __restrict__ gi, int t0, int tc,
    const bf16_t* __restrict__ whh,
    const float* __restrict__ bih, const float* __restrict__ bhh,
    float* __restrict__ hstate, bf16_t* __restrict__ y, float* __restrict__ hT) {
    __shared__ bf16_t gi_lds[16 * 768];       // [b][768]
    __shared__ bf16_t h_lds[2 * 16 * 264];    // [par][b][256+8 pad]

    int dir = blockIdx.x >> 4;
    int b0  = (blockIdx.x & 15) * 16;
    int tid = threadIdx.x;
    int w = tid >> 6, lane = tid & 63, col = lane & 15, quad = lane >> 4;

    bf16x8 wf[3][2][8];
    const bf16_t* wbase = whh + (size_t)dir * G_ * H_;
#pragma unroll
    for (int g = 0; g < 3; g++)
#pragma unroll
        for (int nt = 0; nt < 2; nt++) {
            int row = g * 256 + w * 32 + nt * 16 + col;
#pragma unroll
            for (int kt = 0; kt < 8; kt++)
                wf[g][nt][kt] = *(const bf16x8*)(wbase + (size_t)row * H_ + kt * 32 + quad * 8);
        }
    float brz[2][2], bin_[2], bhn[2];
#pragma unroll
    for (int nt = 0; nt < 2; nt++) {
        int j = w * 32 + nt * 16 + col;
        brz[0][nt] = bih[dir * G_ + j] + bhh[dir * G_ + j];
        brz[1][nt] = bih[dir * G_ + 256 + j] + bhh[dir * G_ + 256 + j];
        bin_[nt]   = bih[dir * G_ + 512 + j];
        bhn[nt]    = bhh[dir * G_ + 512 + j];
    }
    int bb[3], oo[3];
#pragma unroll
    for (int it = 0; it < 3; it++) {
        int c = it * 512 + tid;
        bb[it] = c / 96;
        oo[it] = (c % 96) * 8;
    }
    float hold[2][4];
#pragma unroll
    for (int nt = 0; nt < 2; nt++)
#pragma unroll
        for (int i = 0; i < 4; i++) {
            int j = w * 32 + nt * 16 + col;
            hold[nt][i] = t0 ? hstate[dir * 65536 + (b0 + quad * 4 + i) * 256 + j] : 0.0f;
        }
    for (int i = tid; i < 16 * 264; i += 512) {
        int b = i / 264, j = i % 264;
        float v = (t0 && j < 256) ? hstate[dir * 65536 + (b0 + b) * 256 + j] : 0.0f;
        h_lds[i] = (bf16_t)v;
    }
#pragma unroll
    for (int it = 0; it < 3; it++) {
        int c = it * 512 + tid;
        *(bf16x8*)(&gi_lds[c * 8]) =
            *(const bf16x8*)(gi + ((size_t)0 * B_ + b0 + bb[it]) * DG_ + dir * G_ + oo[it]);
    }
    __syncthreads();

    for (int s = 0; s < tc; s++) {
        int par = s & 1;
        int t = t0 + s;
        int sn = (s + 1 < tc) ? (s + 1) : s;

        bf16x8 pg[3];
#pragma unroll
        for (int it = 0; it < 3; it++)
            pg[it] = *(const bf16x8*)(gi + ((size_t)sn * B_ + b0 + bb[it]) * DG_ + dir * G_ + oo[it]);

        f32x4 acc[3][2] = {};
        const bf16_t* hcur = &h_lds[par * 4224];
#pragma unroll
        for (int kt = 0; kt < 8; kt++) {
            bf16x8 af = *(const bf16x8*)(hcur + col * 264 + kt * 32 + quad * 8);
#pragma unroll
            for (int g = 0; g < 3; g++)
#pragma unroll
                for (int nt = 0; nt < 2; nt++)
                    acc[g][nt] = __builtin_amdgcn_mfma_f32_16x16x32_bf16(af, wf[g][nt][kt], acc[g][nt], 0, 0, 0);
        }

        bf16_t* hnext = &h_lds[(par ^ 1) * 4224];
        int tp = dir ? (T_ - 1 - t) : t;
#pragma unroll
        for (int nt = 0; nt < 2; nt++) {
            int j = w * 32 + nt * 16 + col;
#pragma unroll
            for (int i = 0; i < 4; i++) {
                int b = quad * 4 + i;
                float gr = acc[0][nt][i] + (float)gi_lds[b * 768 + j]       + brz[0][nt];
                float gz = acc[1][nt][i] + (float)gi_lds[b * 768 + 256 + j] + brz[1][nt];
                float gn = (float)gi_lds[b * 768 + 512 + j] + bin_[nt];
                float r = sigm(gr), z = sigm(gz);
                float n = tanh_(gn + r * (acc[2][nt][i] + bhn[nt]));
                float hv = (1.0f - z) * n + z * hold[nt][i];
                hold[nt][i] = hv;
                hnext[b * 264 + j] = (bf16_t)hv;
                if (y) y[((size_t)tp * B_ + b0 + b) * DH_ + dir * H_ + j] = (bf16_t)hv;
                if (t == T_ - 1) hT[(size_t)(b0 + b) * DH_ + dir * H_ + j] = hv;
            }
        }
        __syncthreads();
#pragma unroll
        for (int it = 0; it < 3; it++)
            *(bf16x8*)(&gi_lds[(it * 512 + tid) * 8]) = pg[it];
        __syncthreads();
    }
#pragma unroll
    for (int nt = 0; nt < 2; nt++)
#pragma unroll
        for (int i = 0; i < 4; i++) {
            int j = w * 32 + nt * 16 + col;
            hstate[dir * 65536 + (b0 + quad * 4 + i) * 256 + j] = hold[nt][i];
        }
}

// ------------------------- persistent fused decoder ------------------------
// 128 WGs = 16 batch-groups x 8 j-blocks; every WG does both cells each step.
// h exchange: packed-bf16 buffers, double-buffered by step parity, accessed
// ONLY via per-access coherent atomics (RELAXED/AGENT) -> no cache
// invalidation anywhere; weights stay L1/L2-resident for all 40 phases.

__device__ __forceinline__ void gbar(unsigned int* cnt) {
    __syncthreads();   // compiler drains vmcnt before s_barrier -> stores done
    if (threadIdx.x == 0) {
        __hip_atomic_fetch_add(cnt, 1u, __ATOMIC_RELEASE, __HIP_MEMORY_SCOPE_AGENT);
        unsigned int s = 0;
        while (__hip_atomic_load(cnt, __ATOMIC_RELAXED, __HIP_MEMORY_SCOPE_AGENT) < 8u
               && ++s < (1u << 20))
            __builtin_amdgcn_s_sleep(2);
    }
    __syncthreads();
}

// stage 16 rows x 512 bf16 (16 KB) from coherent global into XOR-swizzled LDS
__device__ __forceinline__ void stage16(bf16_t* lds, const bf16_t* src) {
    const char* s = (const char*)src;
    char* d = (char*)lds;
#pragma unroll
    for (int i2 = 0; i2 < 8; ++i2) {
        int off = i2 * 2048 + threadIdx.x * 8;
        unsigned long long v = __hip_atomic_load(
            (const unsigned long long*)(s + off),
            __ATOMIC_RELAXED, __HIP_MEMORY_SCOPE_AGENT);
        int row = off >> 10;
        int swz = off ^ ((row & 7) << 4);
        *(unsigned long long*)(d + swz) = v;
    }
}

__device__ __forceinline__ bf16x8 fragrd(const bf16_t* lds, int kt, int col, int quad) {
    int byte = (col * 1024 + kt * 64 + quad * 16) ^ ((col & 7) << 4);
    return *(const bf16x8*)((const char*)lds + byte);
}

// publish hv as bf16 into packed u32 pairs (even-col lanes store j, j+1)
__device__ __forceinline__ void publish(bf16_t* dst, int b, int j, float hv, int col) {
    bf16_t hb = (bf16_t)hv;
    unsigned short mb;
    __builtin_memcpy(&mb, &hb, 2);
    unsigned int pv = (unsigned int)__shfl_xor((int)(unsigned int)mb, 1);
    if ((col & 1) == 0) {
        unsigned int word = (unsigned int)mb | (pv << 16);
        __hip_atomic_store((unsigned int*)((char*)dst + (size_t)(b * DH_ + j) * 2),
                           word, __ATOMIC_RELAXED, __HIP_MEMORY_SCOPE_AGENT);
    }
}

__device__ __forceinline__ void cell_step(
    const bf16_t* sh, const bf16_t* sx, bool dox,
    const bf16_t* __restrict__ Wx, const bf16_t* __restrict__ Wh,
    int j, int col, int quad, int grp,
    float br, float bz, float bin_, float bhn,
    float hold[4], bf16_t* hout, float* hist_t) {
    f32x4 aR = {}, aZ = {}, aIN = {}, aHN = {};
#pragma unroll
    for (int kt = 0; kt < 16; ++kt) {
        bf16x8 ah = fragrd(sh, kt, col, quad);
        bf16x8 w0 = *(const bf16x8*)(Wh + (size_t)j * DH_ + kt * 32 + quad * 8);
        bf16x8 w1 = *(const bf16x8*)(Wh + (size_t)(DH_ + j) * DH_ + kt * 32 + quad * 8);
        bf16x8 w2 = *(const bf16x8*)(Wh + (size_t)(2 * DH_ + j) * DH_ + kt * 32 + quad * 8);
        aR  = __builtin_amdgcn_mfma_f32_16x16x32_bf16(ah, w0, aR, 0, 0, 0);
        aZ  = __builtin_amdgcn_mfma_f32_16x16x32_bf16(ah, w1, aZ, 0, 0, 0);
        aHN = __builtin_amdgcn_mfma_f32_16x16x32_bf16(ah, w2, aHN, 0, 0, 0);
        if (dox) {
            bf16x8 ax = fragrd(sx, kt, col, quad);
            bf16x8 x0 = *(const bf16x8*)(Wx + (size_t)j * DH_ + kt * 32 + quad * 8);
            bf16x8 x1 = *(const bf16x8*)(Wx + (size_t)(DH_ + j) * DH_ + kt * 32 + quad * 8);
            bf16x8 x2 = *(const bf16x8*)(Wx + (size_t)(2 * DH_ + j) * DH_ + kt * 32 + quad * 8);
            aR  = __builtin_amdgcn_mfma_f32_16x16x32_bf16(ax, x0, aR, 0, 0, 0);
            aZ  = __builtin_amdgcn_mfma_f32_16x16x32_bf16(ax, x1, aZ, 0, 0, 0);
            aIN = __builtin_amdgcn_mfma_f32_16x16x32_bf16(ax, x2, aIN, 0, 0, 0);
        }
    }
#pragma unroll
    for (int i = 0; i < 4; ++i) {
        int b = grp * 16 + quad * 4 + i;
        float r = sigm(aR[i] + br);
        float z = sigm(aZ[i] + bz);
        float n = tanh_(aIN[i] + bin_ + r * (aHN[i] + bhn));
        float hv = (1.0f - z) * n + z * hold[i];
        hold[i] = hv;
        if (hist_t) hist_t[(size_t)b * DH_ + j] = hv;
        publish(hout, b, j, hv, col);
    }
}

__global__ __launch_bounds__(256) void dec_persist(
    const bf16_t* __restrict__ weff, const float* __restrict__ beff,
    const float* __restrict__ ov,
    const bf16_t* __restrict__ wdhh0, const float* __restrict__ dbhh0,
    const bf16_t* __restrict__ wdih1, const float* __restrict__ dbih1,
    const bf16_t* __restrict__ wdhh1, const float* __restrict__ dbhh1,
    const float* __restrict__ h0init, const float* __restrict__ h1init,
    bf16_t* hx00, bf16_t* hx01, bf16_t* hx10, bf16_t* hx11,
    float* __restrict__ hist, unsigned int* __restrict__ bar) {
    __shared__ bf16_t sh[16 * 512];
    __shared__ bf16_t sx[16 * 512];
    int grp = blockIdx.x & 15;        // partner WGs 16 apart -> same XCD (%8)
    int jblk = blockIdx.x >> 4;
    int tid = threadIdx.x, w = tid >> 6, lane = tid & 63;
    int col = lane & 15, quad = lane >> 4;
    int j = jblk * 64 + w * 16 + col;

    // per-lane folded biases
    float b0r = beff[j] + dbhh0[j],           b0z = beff[DH_ + j] + dbhh0[DH_ + j];
    float b0in = beff[2 * DH_ + j],           b0hn = dbhh0[2 * DH_ + j];
    float o0r = ov[j] + dbhh0[j],             o0z = ov[DH_ + j] + dbhh0[DH_ + j];
    float o0in = ov[2 * DH_ + j];
    float b1r = dbih1[j] + dbhh1[j],          b1z = dbih1[DH_ + j] + dbhh1[DH_ + j];
    float b1in = dbih1[2 * DH_ + j],          b1hn = dbhh1[2 * DH_ + j];

    // fp32 carries in registers; publish initial bf16 state to parity-1 bufs
    float hold0[4], hold1[4];
#pragma unroll
    for (int i = 0; i < 4; ++i) {
        int b = grp * 16 + quad * 4 + i;
        float v0 = h0init[(size_t)b * DH_ + j];
        float v1 = h1init[(size_t)b * DH_ + j];
        hold0[i] = v0; hold1[i] = v1;
        publish(hx01, b, j, v0, col);
        publish(hx11, b, j, v1, col);
    }
    gbar(bar + grp);   // phase 0: init state visible

    int ph = 1;
    for (int t = 0; t < OSL_; ++t) {
        bf16_t* write0 = (t & 1) ? hx01 : hx00;
        bf16_t* read0  = (t & 1) ? hx00 : hx01;
        bf16_t* write1 = (t & 1) ? hx11 : hx10;
        bf16_t* read1  = (t & 1) ? hx10 : hx11;

        // cell0: gi = (t==0 ? ov : Weff@h1(t-1)); gh = h0(t-1)@Whh0^T
        bool dox0 = (t > 0);
        __syncthreads();
        stage16(sh, read0 + (size_t)grp * 16 * DH_);
        if (dox0) stage16(sx, read1 + (size_t)grp * 16 * DH_);
        __syncthreads();
        cell_step(sh, sx, dox0, weff, wdhh0, j, col, quad, grp,
                  dox0 ? b0r : o0r, dox0 ? b0z : o0z, dox0 ? b0in : o0in, b0hn,
                  hold0, write0, nullptr);
        gbar(bar + ph * 16 + grp); ph++;

        // cell1: gi = h0(t)@Wih1^T; gh = h1(t-1)@Whh1^T; writes hist[t]
        __syncthreads();
        stage16(sh, read1 + (size_t)grp * 16 * DH_);
        stage16(sx, write0 + (size_t)grp * 16 * DH_);
        __syncthreads();
        cell_step(sh, sx, true, wdih1, wdhh1, j, col, quad, grp,
                  b1r, b1z, b1in, b1hn,
                  hold1, write1, hist + (size_t)t * B_ * DH_);
        gbar(bar + ph * 16 + grp); ph++;
    }
}

// ------------------------------- FC head -----------------------------------
__global__ __launch_bounds__(256) void fc_all(
    const float* __restrict__ hist, const float* __restrict__ fcw,
    const float* __restrict__ fcb, float* __restrict__ out) {
    int t  = blockIdx.x >> 4;
    int b0 = (blockIdx.x & 15) * 16;
    int tid = threadIdx.x;
    int bl = tid >> 4, o = (tid >> 3) & 1, part = tid & 7;
    const float* hp = hist + ((size_t)t * B_ + b0 + bl) * DH_;
    const float* wp = fcw + o * DH_;
    float s = 0.0f;
    for (int k = part * 64; k < part * 64 + 64; k += 4) {
        f32x4 hv = *(const f32x4*)(hp + k);
        f32x4 wv = *(const f32x4*)(wp + k);
        s += hv[0] * wv[0] + hv[1] * wv[1] + hv[2] * wv[2] + hv[3] * wv[3];
    }
    s += __shfl_down(s, 4); s += __shfl_down(s, 2); s += __shfl_down(s, 1);
    if (part == 0) out[(size_t)(b0 + bl) * (OSL_ * 2) + t * 2 + o] = s + fcb[o];
}

// ------------------------------ launcher -----------------------------------

#define OFF_WIH0E 0ull
#define OFF_WHH0E 196608ull
#define OFF_WIH1E 983040ull
#define OFF_WHH1E 2555904ull
#define OFF_WDHH0 3342336ull
#define OFF_WDIH1 4915200ull
#define OFF_WDHH1 6488064ull
#define OFF_WEFF  8060928ull
#define OFF_BEFF  9633792ull
#define OFF_BAR   9641984ull    // 41 phases x 16 groups (zeroed 1024 u32)
#define OFF_OV    9658368ull
#define OFF_H0A   9682944ull
#define OFF_H0B   10207232ull   // hx00 (256 KB) + hx01 (256 KB)
#define OFF_H1A   10731520ull
#define OFF_H1B   11255808ull   // hx10 (256 KB) + hx11 (256 KB)
#define OFF_HST   11780096ull
#define OFF_HIST  12304384ull
#define OFF_XCAT  22790144ull
#define OFF_GI    157007872ull

extern "C" void kernel_launch(void* const* d_in, const int* in_sizes, int n_in,
                              void* d_out, int out_size, void* d_ws, size_t ws_size,
                              hipStream_t stream) {
    const float* x      = (const float*)d_in[0];
    const float* st     = (const float*)d_in[1];
    const float* eWih0  = (const float*)d_in[2];
    const float* eWhh0  = (const float*)d_in[3];
    const float* ebih0  = (const float*)d_in[4];
    const float* ebhh0  = (const float*)d_in[5];
    const float* eWih1  = (const float*)d_in[6];
    const float* eWhh1  = (const float*)d_in[7];
    const float* ebih1  = (const float*)d_in[8];
    const float* ebhh1  = (const float*)d_in[9];
    const float* dWih0  = (const float*)d_in[10];
    const float* dWhh0  = (const float*)d_in[11];
    const float* dbih0  = (const float*)d_in[12];
    const float* dbhh0  = (const float*)d_in[13];
    const float* dWih1  = (const float*)d_in[14];
    const float* dWhh1  = (const float*)d_in[15];
    const float* dbih1  = (const float*)d_in[16];
    const float* dbhh1  = (const float*)d_in[17];
    const float* fcW    = (const float*)d_in[18];
    const float* fcb    = (const float*)d_in[19];

    char* ws = (char*)d_ws;
    bf16_t* wih0e = (bf16_t*)(ws + OFF_WIH0E);
    bf16_t* whh0e = (bf16_t*)(ws + OFF_WHH0E);
    bf16_t* wih1e = (bf16_t*)(ws + OFF_WIH1E);
    bf16_t* whh1e = (bf16_t*)(ws + OFF_WHH1E);
    bf16_t* wdhh0 = (bf16_t*)(ws + OFF_WDHH0);
    bf16_t* wdih1 = (bf16_t*)(ws + OFF_WDIH1);
    bf16_t* wdhh1 = (bf16_t*)(ws + OFF_WDHH1);
    bf16_t* weff  = (bf16_t*)(ws + OFF_WEFF);
    float*  beff  = (float*)(ws + OFF_BEFF);
    unsigned int* bar = (unsigned int*)(ws + OFF_BAR);
    float*  ovp   = (float*)(ws + OFF_OV);
    float*  h0init = (float*)(ws + OFF_H0A);
    float*  h1init = (float*)(ws + OFF_H1A);
    bf16_t* hx00  = (bf16_t*)(ws + OFF_H0B);
    bf16_t* hx01  = (bf16_t*)(ws + OFF_H0B + 262144ull);
    bf16_t* hx10  = (bf16_t*)(ws + OFF_H1B);
    bf16_t* hx11  = (bf16_t*)(ws + OFF_H1B + 262144ull);
    float*  hstate = (float*)(ws + OFF_HST);
    float*  hist  = (float*)(ws + OFF_HIST);
    bf16_t* xcat  = (bf16_t*)(ws + OFF_XCAT);
    bf16_t* gi    = (bf16_t*)(ws + OFF_GI);

    int Tc = 512;
    while (Tc > 8 && OFF_GI + (unsigned long long)Tc * 786432ull > (unsigned long long)ws_size)
        Tc >>= 1;
    int nch = T_ / Tc;

    prep_all<<<dim3(3072, 8), 256, 0, stream>>>(
        eWih0, eWhh0, eWih1, eWhh1, dWhh0, dWih1, dWhh1,
        wih0e, whh0e, wih1e, whh1e, wdhh0, wdih1, wdhh1,
        dWih0, fcW, fcb, dbih0, st, weff, beff, ovp, bar);

    for (int c = 0; c < nch; c++) {
        gemm_gi<<<dim3(Tc * 2, 12), 256, 0, stream>>>(x, nullptr, wih0e, gi, c * Tc, 64);
        gru_scan<<<32, 512, 0, stream>>>(gi, c * Tc, Tc, whh0e, ebih0, ebhh0, hstate, xcat, h0init);
    }
    for (int c = 0; c < nch; c++) {
        gemm_gi<<<dim3(Tc * 2, 12), 256, 0, stream>>>(nullptr, xcat, wih1e, gi, c * Tc, 512);
        gru_scan<<<32, 512, 0, stream>>>(gi, c * Tc, Tc, whh1e, ebih1, ebhh1, hstate, nullptr, h1init);
    }

    dec_persist<<<128, 256, 0, stream>>>(weff, beff, ovp,
                                         wdhh0, dbhh0, wdih1, dbih1, wdhh1, dbhh1,
                                         h0init, h1init,
                                         hx00, hx01, hx10, hx11,
                                         hist, bar);

    fc_all<<<OSL_ * 16, 256, 0, stream>>>(hist, fcW, fcb, (float*)d_out);
}